// Round 18
// baseline (395.024 us; speedup 1.0000x reference)
//
#include <hip/hip_runtime.h>

#define HIDDEN 2560
#define NHEADS 32
#define HDIM 80
#define DPAD 96
#define SEQ 2048
#define M_TOK 4096
#define N_QKV 7680
#define ATT_SCALE 0.11180339887498949f  // 80^-0.5

typedef __attribute__((ext_vector_type(4))) float f32x4;
typedef __attribute__((ext_vector_type(16))) float f32x16;
typedef __attribute__((ext_vector_type(4))) int i32x4;
typedef __attribute__((ext_vector_type(8))) short bf16x8;
typedef __attribute__((ext_vector_type(8))) unsigned short ushort8;

#define BAR() asm volatile("s_barrier" ::: "memory")

__device__ __forceinline__ unsigned short f2bf(float f) {
    unsigned int u = __float_as_uint(f);
    u += 0x7FFFu + ((u >> 16) & 1u);
    return (unsigned short)(u >> 16);
}
__device__ __forceinline__ float bf2f(unsigned short h) {
    return __uint_as_float(((unsigned int)h) << 16);
}

__device__ __forceinline__ void async_copy16(unsigned short* lds, const unsigned short* g) {
    __builtin_amdgcn_global_load_lds((const __attribute__((address_space(1))) void*)g,
                                     (__attribute__((address_space(3))) void*)lds, 16, 0, 0);
}

__device__ __forceinline__ int cvt_pk_bf16(float lo, float hi) {
    int d;
    asm("v_cvt_pk_bf16_f32 %0, %1, %2" : "=v"(d) : "v"(lo), "v"(hi));
    return d;
}

// ---------------- fp32 -> bf16 convert (8 elems/thread) ----------------
__global__ __launch_bounds__(256) void cvt_kernel(const float* __restrict__ in,
                                                  unsigned short* __restrict__ out, int n8) {
    int i = blockIdx.x * 256 + threadIdx.x;
    if (i >= n8) return;
    const float4* p = (const float4*)in + (size_t)i * 2;
    float4 a = p[0], b = p[1];
    ushort8 o;
    o[0] = f2bf(a.x); o[1] = f2bf(a.y); o[2] = f2bf(a.z); o[3] = f2bf(a.w);
    o[4] = f2bf(b.x); o[5] = f2bf(b.y); o[6] = f2bf(b.z); o[7] = f2bf(b.w);
    *((ushort8*)out + i) = o;
}

// ---------------- fp32 [R][C] -> bf16 [C][R] transpose ----------------
__global__ __launch_bounds__(256) void transpose_kernel(const float* __restrict__ in,
                                                        unsigned short* __restrict__ out,
                                                        int R, int C) {
    __shared__ unsigned short tile[64][66];
    const int r0 = blockIdx.y * 64, c0 = blockIdx.x * 64;
    const int t = threadIdx.x;
#pragma unroll
    for (int rep = 0; rep < 16; ++rep) {
        int idx = rep * 256 + t;
        int i = idx >> 6, j = idx & 63;
        tile[i][j] = f2bf(in[(size_t)(r0 + i) * C + (c0 + j)]);
    }
    __syncthreads();
#pragma unroll
    for (int rep = 0; rep < 16; ++rep) {
        int idx = rep * 256 + t;
        int j = idx >> 6, i = idx & 63;
        out[(size_t)(c0 + j) * R + (r0 + i)] = tile[i][j];
    }
}

// ---------------- 256x256 GEMM v3: 16 waves (4Mx4N), K32 4-slot, 32x32x16 MFMA ----------------
// r13 skeleton (162 us, vmcnt(4) pipeline) with the MFMA shape switched to
// v_mfma_f32_32x32x16_bf16: wave 64x64 = 2x2 of 32x32 tiles, acc[2][2] f32x16 =
// 64 AGPR (same), but 8 frag-reads + 8 MFMA/period (vs 12 + 16) and the 32x32
// shape's higher measured ceiling (2495 vs 2176 TF).
// Operand layout (flash-verified): lane l holds row l&31, k-slice (l>>5)*8..+7
// per K16 chunk. C layout (m74/m101): col = l&31, row = (r&3)+8*(r>>2)+4*(l>>5).
// Staging/swizzle/vmcnt identical to r13.
template <int OUT_BF16>
__global__ __launch_bounds__(1024, 4) void gemm256(const unsigned short* __restrict__ A,
                                                   const unsigned short* __restrict__ Bt,
                                                   const float* __restrict__ bias,
                                                   void* __restrict__ C,
                                                   int M, int N, int K) {
    __shared__ __align__(16) unsigned short S[4][16384];  // [slot]: A 8192 | B 8192 shorts
    const int t = threadIdx.x;
    const int lane = t & 63, wid = t >> 6;
    const int wm = wid >> 2, wn = wid & 3;
    const int l31 = lane & 31, h2 = lane >> 5;

    const int cpx = (int)gridDim.x >> 3;
    const int wg = ((int)blockIdx.x % 8) * cpx + ((int)blockIdx.x >> 3);
    const int bm = (wg & 15) * 256;
    const int bn = (wg >> 4) * 256;

    // staging: per half-tile (A or B) 1024 x 16B chunks; thread t -> chunk t
    const int srow = t >> 2;
    const int scol = ((t & 3) ^ ((srow >> 1) & 3)) * 8;  // pre-swizzled source chunk
    const unsigned short* Abase = A + (size_t)bm * K;
    const unsigned short* Bbase = Bt + (size_t)bn * K;
    const int NP = K >> 5;  // K32 periods

    // fragment offsets: [tile][k-half]; row = wbase + tile*32 + l31,
    // logical chunk = kk*2 + h2, phys = logical ^ ((row>>1)&3)
    int aoff[2][2], boff[2][2];
#pragma unroll
    for (int mi = 0; mi < 2; ++mi) {
        int r = wm * 64 + mi * 32 + l31;
#pragma unroll
        for (int kk = 0; kk < 2; ++kk)
            aoff[mi][kk] = r * 32 + (((kk * 2 + h2) ^ ((r >> 1) & 3)) * 8);
    }
#pragma unroll
    for (int ni = 0; ni < 2; ++ni) {
        int r = wn * 64 + ni * 32 + l31;
#pragma unroll
        for (int kk = 0; kk < 2; ++kk)
            boff[ni][kk] = 8192 + r * 32 + (((kk * 2 + h2) ^ ((r >> 1) & 3)) * 8);
    }

    f32x16 acc[2][2] = {};

#define STAGE_A(J) { const int j_ = (J);                                               \
    async_copy16(&S[j_ & 3][0] + t * 8,                                                \
                 Abase + (size_t)srow * K + j_ * 32 + scol); }
#define STAGE_B(J) { const int j_ = (J);                                               \
    async_copy16(&S[j_ & 3][8192] + t * 8,                                             \
                 Bbase + (size_t)srow * K + j_ * 32 + scol); }

#define PERIOD(J, VM, DOSTAGE) {                                                       \
    const int jp_ = (J);                                                               \
    asm volatile("s_waitcnt vmcnt(" #VM ")" ::: "memory");                             \
    BAR();                                                                             \
    const unsigned short* sl = &S[jp_ & 3][0];                                         \
    if (DOSTAGE) STAGE_A(jp_ + 3);                                                     \
    bf16x8 bfr[2][2], afr[2];                                                          \
    _Pragma("unroll")                                                                  \
    for (int ni = 0; ni < 2; ++ni)                                                     \
        _Pragma("unroll")                                                              \
        for (int kk = 0; kk < 2; ++kk)                                                 \
            bfr[ni][kk] = *(const bf16x8*)(sl + boff[ni][kk]);                         \
    afr[0] = *(const bf16x8*)(sl + aoff[0][0]);                                        \
    afr[1] = *(const bf16x8*)(sl + aoff[0][1]);                                        \
    __builtin_amdgcn_s_setprio(1);                                                     \
    _Pragma("unroll")                                                                  \
    for (int ni = 0; ni < 2; ++ni)                                                     \
        _Pragma("unroll")                                                              \
        for (int kk = 0; kk < 2; ++kk)                                                 \
            acc[0][ni] = __builtin_amdgcn_mfma_f32_32x32x16_bf16(afr[kk], bfr[ni][kk], \
                                                                 acc[0][ni], 0, 0, 0); \
    __builtin_amdgcn_s_setprio(0);                                                     \
    if (DOSTAGE) STAGE_B(jp_ + 3);                                                     \
    afr[0] = *(const bf16x8*)(sl + aoff[1][0]);                                        \
    afr[1] = *(const bf16x8*)(sl + aoff[1][1]);                                        \
    __builtin_amdgcn_s_setprio(1);                                                     \
    _Pragma("unroll")                                                                  \
    for (int ni = 0; ni < 2; ++ni)                                                     \
        _Pragma("unroll")                                                              \
        for (int kk = 0; kk < 2; ++kk)                                                 \
            acc[1][ni] = __builtin_amdgcn_mfma_f32_32x32x16_bf16(afr[kk], bfr[ni][kk], \
                                                                 acc[1][ni], 0, 0, 0); \
    __builtin_amdgcn_s_setprio(0); }

    // prologue: stage periods 0,1,2 (6 loads/thread outstanding)
    STAGE_A(0); STAGE_B(0);
    STAGE_A(1); STAGE_B(1);
    STAGE_A(2); STAGE_B(2);

    for (int p = 0; p < NP - 3; ++p) {
        PERIOD(p, 4, 1);  // stages p+3 (last: NP-1)
    }
    PERIOD(NP - 3, 4, 0);
    PERIOD(NP - 2, 2, 0);
    PERIOD(NP - 1, 0, 0);

#undef PERIOD
#undef STAGE_A
#undef STAGE_B

#pragma unroll
    for (int ni = 0; ni < 2; ++ni) {
        const int col = bn + wn * 64 + ni * 32 + l31;
        const float bv = bias[col];
#pragma unroll
        for (int mi = 0; mi < 2; ++mi) {
#pragma unroll
            for (int r = 0; r < 16; ++r) {
                const int row = bm + wm * 64 + mi * 32 + (r & 3) + 8 * (r >> 2) + 4 * h2;
                float v = acc[mi][ni][r] + bv;
                if (OUT_BF16)
                    ((unsigned short*)C)[(size_t)row * N + col] = f2bf(v);
                else
                    ((float*)C)[(size_t)row * N + col] = v;
            }
        }
    }
}

// ---------------- 256x160 GEMM for the down-proj: 256 blocks = 1 balanced round ----------------
__global__ __launch_bounds__(1024, 4) void gemm160(const unsigned short* __restrict__ A,
                                                   const unsigned short* __restrict__ Bt,
                                                   const float* __restrict__ bias,
                                                   float* __restrict__ C,
                                                   int M, int N, int K) {
    __shared__ __align__(16) unsigned short S[4][13312];  // [slot]: A 8192 | B 5120 shorts
    const int t = threadIdx.x;
    const int lane = t & 63, wid = t >> 6;
    const int wm = wid >> 1, wn = wid & 1;
    const int l15 = lane & 15, lhi = lane >> 4;

    const int cpx = (int)gridDim.x >> 3;
    const int wg = ((int)blockIdx.x % 8) * cpx + ((int)blockIdx.x >> 3);
    const int bm = (wg & 15) * 256;
    const int bn = (wg >> 4) * 160;

    const int srow = t >> 2;
    const int scol = ((t & 3) ^ ((srow >> 1) & 3)) * 8;      // A chunk (1024 chunks)
    const int bidx = (t < 640) ? t : (t - 640);              // B chunk (640, dup 0..383)
    const int brow = bidx >> 2;
    const int bcol = ((bidx & 3) ^ ((brow >> 1) & 3)) * 8;
    const unsigned short* Abase = A + (size_t)bm * K;
    const unsigned short* Bbase = Bt + (size_t)bn * K;
    const int NP = K >> 5;

    int aoff[2], boff[5];
#pragma unroll
    for (int i = 0; i < 2; ++i) {
        int r = wm * 32 + i * 16 + l15;
        aoff[i] = r * 32 + ((lhi ^ ((r >> 1) & 3)) * 8);
    }
#pragma unroll
    for (int f = 0; f < 5; ++f) {
        int r = wn * 80 + f * 16 + l15;
        boff[f] = 8192 + r * 32 + ((lhi ^ ((r >> 1) & 3)) * 8);
    }

    f32x4 acc[2][5] = {};

#define STAGE_A(J) { const int j_ = (J);                                               \
    async_copy16(&S[j_ & 3][0] + t * 8,                                                \
                 Abase + (size_t)srow * K + j_ * 32 + scol); }
#define STAGE_B(J) { const int j_ = (J);                                               \
    async_copy16(&S[j_ & 3][8192] + bidx * 8,                                          \
                 Bbase + (size_t)brow * K + j_ * 32 + bcol); }

#define PERIOD(J, VM, DOSTAGE) {                                                       \
    const int jp_ = (J);                                                               \
    asm volatile("s_waitcnt vmcnt(" #VM ")" ::: "memory");                             \
    BAR();                                                                             \
    const unsigned short* sl = &S[jp_ & 3][0];                                         \
    if (DOSTAGE) STAGE_A(jp_ + 3);                                                     \
    bf16x8 bq[5], afr[2];                                                              \
    _Pragma("unroll")                                                                  \
    for (int f = 0; f < 5; ++f) bq[f] = *(const bf16x8*)(sl + boff[f]);                \
    afr[0] = *(const bf16x8*)(sl + aoff[0]);                                           \
    afr[1] = *(const bf16x8*)(sl + aoff[1]);                                           \
    if (DOSTAGE) STAGE_B(jp_ + 3);                                                     \
    __builtin_amdgcn_s_setprio(1);                                                     \
    _Pragma("unroll")                                                                  \
    for (int i = 0; i < 2; ++i)                                                        \
        _Pragma("unroll")                                                              \
        for (int f = 0; f < 5; ++f)                                                    \
            acc[i][f] = __builtin_amdgcn_mfma_f32_16x16x32_bf16(afr[i], bq[f],         \
                                                                acc[i][f], 0, 0, 0);   \
    __builtin_amdgcn_s_setprio(0); }

    STAGE_A(0); STAGE_B(0);
    STAGE_A(1); STAGE_B(1);
    STAGE_A(2); STAGE_B(2);

    for (int p = 0; p < NP - 3; ++p) {
        PERIOD(p, 4, 1);
    }
    PERIOD(NP - 3, 4, 0);
    PERIOD(NP - 2, 2, 0);
    PERIOD(NP - 1, 0, 0);

#undef PERIOD
#undef STAGE_A
#undef STAGE_B

#pragma unroll
    for (int f = 0; f < 5; ++f) {
        const int col = bn + wn * 80 + f * 16 + l15;
        const float bv = bias[col];
#pragma unroll
        for (int i = 0; i < 2; ++i) {
            const int row0 = bm + wm * 32 + i * 16 + lhi * 4;
#pragma unroll
            for (int r = 0; r < 4; ++r)
                C[(size_t)(row0 + r) * N + col] = acc[i][f][r] + bv;
        }
    }
}

// ---------------- pack qkv -> Q (rope+scale), K (rope), Vt; DPAD layout, pads unread ----------------
__global__ __launch_bounds__(256) void pack_rope_kernel(const unsigned short* __restrict__ qkv,
                                                        const int* __restrict__ pos_ids,
                                                        unsigned short* __restrict__ Qb,
                                                        unsigned short* __restrict__ Kb,
                                                        unsigned short* __restrict__ Vt) {
    int g = blockIdx.x * 256 + threadIdx.x;  // (b*32+h)*2048 + s
    int s = g & (SEQ - 1);
    int bh = g >> 11;
    int b = bh >> 5;
    int h = bh & 31;
    int m = b * SEQ + s;
    const unsigned short* base = qkv + (size_t)m * N_QKV + h * HDIM;
    unsigned short* Qrow = Qb + ((size_t)bh * SEQ + s) * DPAD;
    unsigned short* Krow = Kb + ((size_t)bh * SEQ + s) * DPAD;
    unsigned short* Vcol = Vt + (size_t)bh * HDIM * SEQ + s;

    float pos = (float)pos_ids[m];
    float qv[32], kv[32];
#pragma unroll
    for (int c = 0; c < 4; ++c) {
        ushort8 qc = *(const ushort8*)(base + c * 8);
        ushort8 kc = *(const ushort8*)(base + HIDDEN + c * 8);
#pragma unroll
        for (int j = 0; j < 8; ++j) {
            qv[c * 8 + j] = bf2f(qc[j]);
            kv[c * 8 + j] = bf2f(kc[j]);
        }
    }
#pragma unroll
    for (int d = 0; d < 16; ++d) {
        float inv = __expf(-(float)d * 0.5756462732485115f);  // ln(10000)/16
        float ang = pos * inv;
        float sn, cs;
        __sincosf(ang, &sn, &cs);
        float qcs = cs * ATT_SCALE, qsn = sn * ATT_SCALE;  // fold softmax scale into Q
        float x1 = qv[d], x2 = qv[d + 16];
        qv[d] = x1 * qcs - x2 * qsn;
        qv[d + 16] = x2 * qcs + x1 * qsn;
        x1 = kv[d]; x2 = kv[d + 16];
        kv[d] = x1 * cs - x2 * sn;
        kv[d + 16] = x2 * cs + x1 * sn;
    }
#pragma unroll
    for (int c = 0; c < 4; ++c) {
        ushort8 qo, ko;
#pragma unroll
        for (int j = 0; j < 8; ++j) {
            qo[j] = f2bf(qv[c * 8 + j]);
            ko[j] = f2bf(kv[c * 8 + j]);
        }
        *(ushort8*)(Qrow + c * 8) = qo;
        *(ushort8*)(Krow + c * 8) = ko;
    }
#pragma unroll
    for (int c = 4; c < 10; ++c) {
        ushort8 qc = *(const ushort8*)(base + c * 8);
        ushort8 qo;
#pragma unroll
        for (int j = 0; j < 8; ++j) qo[j] = f2bf(bf2f(qc[j]) * ATT_SCALE);
        *(ushort8*)(Qrow + c * 8) = qo;
        *(ushort8*)(Krow + c * 8) = *(const ushort8*)(base + HIDDEN + c * 8);
    }
    // pad columns 80..95 never read by flash -> no zero-fill
#pragma unroll
    for (int d = 0; d < HDIM; ++d) Vcol[(size_t)d * SEQ] = base[2 * HIDDEN + d];
}

// ---------------- causal flash attention v3.1: swapped QK^T, in-register softmax, D=80 exact ----------------
__global__ __launch_bounds__(512) void flash_kernel(const unsigned short* __restrict__ Qb,
                                                    const unsigned short* __restrict__ Kb,
                                                    const unsigned short* __restrict__ Vt,
                                                    unsigned short* __restrict__ attn) {
    __shared__ __align__(16) unsigned short Klds[64 * 128];
    __shared__ __align__(16) unsigned short Vlds[96 * 64];

    const int bh = blockIdx.x;
    const int qb = 7 - (int)blockIdx.y;  // heavy blocks dispatch first
    const int q0b = qb * 256;
    const int nkt = 4 * qb + 4;
    const int t = threadIdx.x;
    const int lane = t & 63, wid = t >> 6;
    const int l31 = lane & 31, h = lane >> 5, l7 = lane & 7;
    const int q0w = q0b + wid * 32;
    const int swz = l7 << 3;  // xor on shorts-offset (== (row&7)<<4 bytes)

    const unsigned short* Kbase = Kb + (size_t)bh * SEQ * DPAD;
    const unsigned short* Vbase = Vt + (size_t)bh * HDIM * SEQ;

    bf16x8 qf[5];
    {
        const unsigned short* Qrow = Qb + ((size_t)bh * SEQ + q0w + l31) * DPAD + h * 8;
#pragma unroll
        for (int dc = 0; dc < 5; ++dc) qf[dc] = *(const bf16x8*)(Qrow + dc * 16);
    }

    ((int*)Vlds)[2560 + t] = 0;  // zero V pad rows 80..95

    f32x16 acc0 = {}, acc1 = {}, acc2 = {};
    float mrow = -1e30f, lrow = 0.f;

    const int kidx1 = 512 + t;
    const int kr0 = t / 10, kc0 = t % 10;
    const int kr1 = kidx1 / 10, kc1 = kidx1 % 10;
    const int vr0 = t >> 3, vc0 = t & 7;
    const int vr1 = (512 + t) >> 3, vc1 = t & 7;
    const int kd0 = kr0 * 128 + ((kc0 * 8) ^ ((kr0 & 7) << 3));
    const int kd1 = kr1 * 128 + ((kc1 * 8) ^ ((kr1 & 7) << 3));
    const int vd0 = vr0 * 64 + ((vc0 * 8) ^ ((vr0 & 7) << 3));
    const int vd1 = vr1 * 64 + ((vc1 * 8) ^ ((vr1 & 7) << 3));

    ushort8 kreg0, kreg1, vreg0, vreg1;
    kreg0 = *(const ushort8*)(Kbase + (size_t)kr0 * DPAD + kc0 * 8);
    if (t < 128) kreg1 = *(const ushort8*)(Kbase + (size_t)kr1 * DPAD + kc1 * 8);
    vreg0 = *(const ushort8*)(Vbase + (size_t)vr0 * SEQ + vc0 * 8);
    if (t < 128) vreg1 = *(const ushort8*)(Vbase + (size_t)vr1 * SEQ + vc1 * 8);

    for (int kt = 0; kt < nkt; ++kt) {
        const int k0 = kt * 64;
        __syncthreads();
        *(ushort8*)(Klds + kd0) = kreg0;
        if (t < 128) *(ushort8*)(Klds + kd1) = kreg1;
        *(ushort8*)(Vlds + vd0) = vreg0;
        if (t < 128) *(ushort8*)(Vlds + vd1) = vreg1;
        __syncthreads();
        if (kt + 1 < nkt) {
            const int kn = k0 + 64;
            kreg0 = *(const ushort8*)(Kbase + (size_t)(kn + kr0) * DPAD + kc0 * 8);
            if (t < 128) kreg1 = *(const ushort8*)(Kbase + (size_t)(kn + kr1) * DPAD + kc1 * 8);
            vreg0 = *(const ushort8*)(Vbase + (size_t)vr0 * SEQ + kn + vc0 * 8);
            if (t < 128) vreg1 = *(const ushort8*)(Vbase + (size_t)vr1 * SEQ + kn + vc1 * 8);
        }
        if (k0 > q0w + 31) continue;

        f32x16 s0 = {}, s1 = {};
        __builtin_amdgcn_s_setprio(1);
#pragma unroll
        for (int dc = 0; dc < 5; ++dc) {
            const int co = (dc * 16 + h * 8) ^ swz;
            bf16x8 ka = *(const bf16x8*)(Klds + l31 * 128 + co);
            bf16x8 kb2 = *(const bf16x8*)(Klds + (32 + l31) * 128 + co);
            s0 = __builtin_amdgcn_mfma_f32_32x32x16_bf16(ka, qf[dc], s0, 0, 0, 0);
            s1 = __builtin_amdgcn_mfma_f32_32x32x16_bf16(kb2, qf[dc], s1, 0, 0, 0);
        }
        __builtin_amdgcn_s_setprio(0);

        const int qg = q0w + l31;
        if (k0 + 63 > q0w) {
#pragma unroll
            for (int r = 0; r < 16; ++r) {
                const int kg = k0 + (r & 3) + 8 * (r >> 2) + 4 * h;
                if (kg > qg) s0[r] = -2e30f;
                if (kg + 32 > qg) s1[r] = -2e30f;
            }
        }
        float pmax = s0[0];
#pragma unroll
        for (int r = 1; r < 16; ++r) pmax = fmaxf(pmax, s0[r]);
#pragma unroll
        for (int r = 0; r < 16; ++r) pmax = fmaxf(pmax, s1[r]);
        pmax = fmaxf(pmax, __shfl_xor(pmax, 32, 64));
        if (!__all(pmax <= mrow + 8.0f)) {
            float mnew = fmaxf(mrow, pmax);
            float scl = __expf(mrow - mnew);
            mrow = mnew;
            lrow *= scl;
#pragma unroll
            for (int r = 0; r < 16; ++r) {
                float sq = __shfl(scl, (r & 3) + 8 * (r >> 2) + 4 * h, 64);
                acc0[r] *= sq; acc1[r] *= sq; acc2[r] *= sq;
            }
        }
        float ps = 0.f;
#pragma unroll
        for (int r = 0; r < 16; ++r) { s0[r] = __expf(s0[r] - mrow); ps += s0[r]; }
#pragma unroll
        for (int r = 0; r < 16; ++r) { s1[r] = __expf(s1[r] - mrow); ps += s1[r]; }
        lrow += ps + __shfl_xor(ps, 32, 64);
        i32x4 af[2][2];
#pragma unroll
        for (int ks = 0; ks < 2; ++ks) {
            const f32x16& sv = ks ? s1 : s0;
            int pk0[2], pk1[2], pk2[2], pk3[2];
#pragma unroll
            for (int i = 0; i < 2; ++i) {
                pk0[i] = cvt_pk_bf16(sv[2 * i], sv[2 * i + 1]);
                pk1[i] = cvt_pk_bf16(sv[4 + 2 * i], sv[5 + 2 * i]);
                pk2[i] = cvt_pk_bf16(sv[8 + 2 * i], sv[9 + 2 * i]);
                pk3[i] = cvt_pk_bf16(sv[12 + 2 * i], sv[13 + 2 * i]);
            }
#pragma unroll
            for (int i = 0; i < 2; ++i) {
                const int o0 = __shfl_xor(pk0[i], 32, 64);
                const int o1 = __shfl_xor(pk1[i], 32, 64);
                af[ks][0][i]     = h ? o1     : pk0[i];
                af[ks][0][2 + i] = h ? pk1[i] : o0;
                const int o2 = __shfl_xor(pk2[i], 32, 64);
                const int o3 = __shfl_xor(pk3[i], 32, 64);
                af[ks][1][i]     = h ? o3     : pk2[i];
                af[ks][1][2 + i] = h ? pk3[i] : o2;
            }
        }
        __builtin_amdgcn_s_setprio(1);
#pragma unroll
        for (int ds = 0; ds < 3; ++ds) {
            f32x16& ac = ds == 0 ? acc0 : (ds == 1 ? acc1 : acc2);
            const int vrow = (ds * 32 + l31) * 64;
#pragma unroll
            for (int ks = 0; ks < 2; ++ks)
#pragma unroll
                for (int kh = 0; kh < 2; ++kh) {
                    bf16x8 vb = *(const bf16x8*)(Vlds + vrow + ((ks * 32 + kh * 16 + h * 8) ^ swz));
                    bf16x8 pa = __builtin_bit_cast(bf16x8, af[ks][kh]);
                    ac = __builtin_amdgcn_mfma_f32_32x32x16_bf16(pa, vb, ac, 0, 0, 0);
                }
        }
        __builtin_amdgcn_s_setprio(0);
    }

    const int hh = bh & 31, b = bh >> 5;
    const float linv = 1.0f / lrow;
#pragma unroll
    for (int r = 0; r < 16; ++r) {
        const int ql = (r & 3) + 8 * (r >> 2) + 4 * h;
        const float lv = __shfl(linv, ql, 64);
        const int row = b * SEQ + q0b + wid * 32 + ql;
        unsigned short* orow = attn + (size_t)row * HIDDEN + hh * HDIM;
        orow[l31] = f2bf(acc0[r] * lv);
        orow[32 + l31] = f2bf(acc1[r] * lv);
        if (l31 < 16) orow[64 + l31] = f2bf(acc2[r] * lv);
    }
}

extern "C" void kernel_launch(void* const* d_in, const int* in_sizes, int n_in,
                              void* d_out, int out_size, void* d_ws, size_t ws_size,
                              hipStream_t stream) {
    const int* pos = (const int*)d_in[0];
    const float* hid = (const float*)d_in[1];
    const float* Wqkv = (const float*)d_in[2];
    const float* bqkv = (const float*)d_in[3];
    const float* Wd = (const float*)d_in[4];
    const float* bd = (const float*)d_in[5];
    float* out = (float*)d_out;
    char* ws = (char*)d_ws;

    unsigned short* WqkvT = (unsigned short*)(ws);                // 39,321,600 B
    unsigned short* WdT   = (unsigned short*)(ws + 39321600);     // 13,107,200 B
    unsigned short* Xbf   = (unsigned short*)(ws + 52428800);     // 20,971,520 B
    unsigned short* qkv   = (unsigned short*)(ws + 73400320);     // 62,914,560 B
    unsigned short* Qbuf  = (unsigned short*)(ws + 136314880);    // 25,165,824 B
    unsigned short* Kbuf  = (unsigned short*)(ws + 161480704);    // 25,165,824 B
    unsigned short* Vt    = (unsigned short*)(ws + 186646528);    // 20,971,520 B
    unsigned short* attnb = Xbf;  // Xbf dead after gemm1; reuse for attention output

    cvt_kernel<<<(M_TOK * HIDDEN / 8 + 255) / 256, 256, 0, stream>>>(hid, Xbf, M_TOK * HIDDEN / 8);
    transpose_kernel<<<dim3(N_QKV / 64, HIDDEN / 64), 256, 0, stream>>>(Wqkv, WqkvT, HIDDEN, N_QKV);
    transpose_kernel<<<dim3(HIDDEN / 64, HIDDEN / 64), 256, 0, stream>>>(Wd, WdT, HIDDEN, HIDDEN);
    gemm256<1><<<(M_TOK / 256) * (N_QKV / 256), 1024, 0, stream>>>(Xbf, WqkvT, bqkv, qkv,
                                                                   M_TOK, N_QKV, HIDDEN);
    pack_rope_kernel<<<(64 * SEQ) / 256, 256, 0, stream>>>(qkv, pos, Qbuf, Kbuf, Vt);
    flash_kernel<<<dim3(64, 8), 512, 0, stream>>>(Qbuf, Kbuf, Vt, attnb);
    gemm160<<<(M_TOK / 256) * (HIDDEN / 160), 1024, 0, stream>>>(attnb, WdT, bd, out,
                                                                 M_TOK, HIDDEN, HIDDEN);
}

// Round 19
// 376.124 us; speedup vs baseline: 1.0502x; 1.0502x over previous
//
#include <hip/hip_runtime.h>

#define HIDDEN 2560
#define NHEADS 32
#define HDIM 80
#define DPAD 96
#define SEQ 2048
#define M_TOK 4096
#define N_QKV 7680
#define ATT_SCALE 0.11180339887498949f  // 80^-0.5

typedef __attribute__((ext_vector_type(4))) float f32x4;
typedef __attribute__((ext_vector_type(16))) float f32x16;
typedef __attribute__((ext_vector_type(4))) int i32x4;
typedef __attribute__((ext_vector_type(8))) short bf16x8;
typedef __attribute__((ext_vector_type(8))) unsigned short ushort8;

#define BAR() asm volatile("s_barrier" ::: "memory")

__device__ __forceinline__ unsigned short f2bf(float f) {
    unsigned int u = __float_as_uint(f);
    u += 0x7FFFu + ((u >> 16) & 1u);
    return (unsigned short)(u >> 16);
}
__device__ __forceinline__ float bf2f(unsigned short h) {
    return __uint_as_float(((unsigned int)h) << 16);
}

__device__ __forceinline__ void async_copy16(unsigned short* lds, const unsigned short* g) {
    __builtin_amdgcn_global_load_lds((const __attribute__((address_space(1))) void*)g,
                                     (__attribute__((address_space(3))) void*)lds, 16, 0, 0);
}

__device__ __forceinline__ int cvt_pk_bf16(float lo, float hi) {
    int d;
    asm("v_cvt_pk_bf16_f32 %0, %1, %2" : "=v"(d) : "v"(lo), "v"(hi));
    return d;
}

// ---------------- fp32 -> bf16 convert (8 elems/thread) ----------------
__global__ __launch_bounds__(256) void cvt_kernel(const float* __restrict__ in,
                                                  unsigned short* __restrict__ out, int n8) {
    int i = blockIdx.x * 256 + threadIdx.x;
    if (i >= n8) return;
    const float4* p = (const float4*)in + (size_t)i * 2;
    float4 a = p[0], b = p[1];
    ushort8 o;
    o[0] = f2bf(a.x); o[1] = f2bf(a.y); o[2] = f2bf(a.z); o[3] = f2bf(a.w);
    o[4] = f2bf(b.x); o[5] = f2bf(b.y); o[6] = f2bf(b.z); o[7] = f2bf(b.w);
    *((ushort8*)out + i) = o;
}

// ---------------- fp32 [R][C] -> bf16 [C][R] transpose ----------------
__global__ __launch_bounds__(256) void transpose_kernel(const float* __restrict__ in,
                                                        unsigned short* __restrict__ out,
                                                        int R, int C) {
    __shared__ unsigned short tile[64][66];
    const int r0 = blockIdx.y * 64, c0 = blockIdx.x * 64;
    const int t = threadIdx.x;
#pragma unroll
    for (int rep = 0; rep < 16; ++rep) {
        int idx = rep * 256 + t;
        int i = idx >> 6, j = idx & 63;
        tile[i][j] = f2bf(in[(size_t)(r0 + i) * C + (c0 + j)]);
    }
    __syncthreads();
#pragma unroll
    for (int rep = 0; rep < 16; ++rep) {
        int idx = rep * 256 + t;
        int j = idx >> 6, i = idx & 63;
        out[(size_t)(c0 + j) * R + (r0 + i)] = tile[i][j];
    }
}

// ---------------- 256x256 GEMM v2: 1024 thr / 16 waves (4Mx4N), K32 4-slot pipeline ----------------
// (round-13/17 proven optimum: 162 us on gemm1, MfmaUtil 45%, VGPR 64, no spill.
//  r18 lesson: 32x32 MFMA frag-reads [32 consecutive rows x 1 chunk] defeat the
//  2-bit chunk swizzle -> inherent 4-way bank conflict; 16x16's [16 rows x 4
//  chunks] pattern exactly tiles the banks. Keep 16x16.)
template <int OUT_BF16>
__global__ __launch_bounds__(1024, 4) void gemm256(const unsigned short* __restrict__ A,
                                                   const unsigned short* __restrict__ Bt,
                                                   const float* __restrict__ bias,
                                                   void* __restrict__ C,
                                                   int M, int N, int K) {
    __shared__ __align__(16) unsigned short S[4][16384];  // [slot]: A 8192 | B 8192 shorts
    const int t = threadIdx.x;
    const int lane = t & 63, wid = t >> 6;
    const int wm = wid >> 2, wn = wid & 3;
    const int l15 = lane & 15, lhi = lane >> 4;

    const int cpx = (int)gridDim.x >> 3;
    const int wg = ((int)blockIdx.x % 8) * cpx + ((int)blockIdx.x >> 3);
    const int bm = (wg & 15) * 256;
    const int bn = (wg >> 4) * 256;

    const int srow = t >> 2;
    const int scol = ((t & 3) ^ ((srow >> 1) & 3)) * 8;  // pre-swizzled source chunk
    const unsigned short* Abase = A + (size_t)bm * K;
    const unsigned short* Bbase = Bt + (size_t)bn * K;
    const int NP = K >> 5;  // K32 periods

    int aoff[4], boff[4];
#pragma unroll
    for (int i = 0; i < 4; ++i) {
        int r = wm * 64 + i * 16 + l15;
        aoff[i] = r * 32 + ((lhi ^ ((r >> 1) & 3)) * 8);
    }
#pragma unroll
    for (int f = 0; f < 4; ++f) {
        int r = wn * 64 + f * 16 + l15;
        boff[f] = 8192 + r * 32 + ((lhi ^ ((r >> 1) & 3)) * 8);
    }

    f32x4 acc[4][4] = {};

#define STAGE_A(J) { const int j_ = (J);                                               \
    async_copy16(&S[j_ & 3][0] + t * 8,                                                \
                 Abase + (size_t)srow * K + j_ * 32 + scol); }
#define STAGE_B(J) { const int j_ = (J);                                               \
    async_copy16(&S[j_ & 3][8192] + t * 8,                                             \
                 Bbase + (size_t)srow * K + j_ * 32 + scol); }

#define PERIOD(J, VM, DOSTAGE) {                                                       \
    const int jp_ = (J);                                                               \
    asm volatile("s_waitcnt vmcnt(" #VM ")" ::: "memory");                             \
    BAR();                                                                             \
    const unsigned short* sl = &S[jp_ & 3][0];                                         \
    if (DOSTAGE) STAGE_A(jp_ + 3);                                                     \
    bf16x8 bq[4], afr[2];                                                              \
    _Pragma("unroll")                                                                  \
    for (int f = 0; f < 4; ++f) bq[f] = *(const bf16x8*)(sl + boff[f]);                \
    afr[0] = *(const bf16x8*)(sl + aoff[0]);                                           \
    afr[1] = *(const bf16x8*)(sl + aoff[1]);                                           \
    __builtin_amdgcn_s_setprio(1);                                                     \
    _Pragma("unroll")                                                                  \
    for (int i = 0; i < 2; ++i)                                                        \
        _Pragma("unroll")                                                              \
        for (int f = 0; f < 4; ++f)                                                    \
            acc[i][f] = __builtin_amdgcn_mfma_f32_16x16x32_bf16(afr[i], bq[f],         \
                                                                acc[i][f], 0, 0, 0);   \
    __builtin_amdgcn_s_setprio(0);                                                     \
    if (DOSTAGE) STAGE_B(jp_ + 3);                                                     \
    afr[0] = *(const bf16x8*)(sl + aoff[2]);                                           \
    afr[1] = *(const bf16x8*)(sl + aoff[3]);                                           \
    __builtin_amdgcn_s_setprio(1);                                                     \
    _Pragma("unroll")                                                                  \
    for (int i = 0; i < 2; ++i)                                                        \
        _Pragma("unroll")                                                              \
        for (int f = 0; f < 4; ++f)                                                    \
            acc[2 + i][f] = __builtin_amdgcn_mfma_f32_16x16x32_bf16(afr[i], bq[f],     \
                                                                    acc[2 + i][f],     \
                                                                    0, 0, 0);          \
    __builtin_amdgcn_s_setprio(0); }

    STAGE_A(0); STAGE_B(0);
    STAGE_A(1); STAGE_B(1);
    STAGE_A(2); STAGE_B(2);

    for (int p = 0; p < NP - 3; ++p) {
        PERIOD(p, 4, 1);  // stages p+3 (last: NP-1)
    }
    PERIOD(NP - 3, 4, 0);
    PERIOD(NP - 2, 2, 0);
    PERIOD(NP - 1, 0, 0);

#undef PERIOD
#undef STAGE_A
#undef STAGE_B

#pragma unroll
    for (int f = 0; f < 4; ++f) {
        const int col = bn + wn * 64 + f * 16 + l15;
        const float bv = bias[col];
#pragma unroll
        for (int i = 0; i < 4; ++i) {
            const int row0 = bm + wm * 64 + i * 16 + lhi * 4;
#pragma unroll
            for (int r = 0; r < 4; ++r) {
                float v = acc[i][f][r] + bv;
                if (OUT_BF16)
                    ((unsigned short*)C)[(size_t)(row0 + r) * N + col] = f2bf(v);
                else
                    ((float*)C)[(size_t)(row0 + r) * N + col] = v;
            }
        }
    }
}

// ---------------- 256x160 GEMM for the down-proj: 256 blocks = 1 balanced round ----------------
__global__ __launch_bounds__(1024, 4) void gemm160(const unsigned short* __restrict__ A,
                                                   const unsigned short* __restrict__ Bt,
                                                   const float* __restrict__ bias,
                                                   float* __restrict__ C,
                                                   int M, int N, int K) {
    __shared__ __align__(16) unsigned short S[4][13312];  // [slot]: A 8192 | B 5120 shorts
    const int t = threadIdx.x;
    const int lane = t & 63, wid = t >> 6;
    const int wm = wid >> 1, wn = wid & 1;
    const int l15 = lane & 15, lhi = lane >> 4;

    const int cpx = (int)gridDim.x >> 3;
    const int wg = ((int)blockIdx.x % 8) * cpx + ((int)blockIdx.x >> 3);
    const int bm = (wg & 15) * 256;
    const int bn = (wg >> 4) * 160;

    const int srow = t >> 2;
    const int scol = ((t & 3) ^ ((srow >> 1) & 3)) * 8;      // A chunk (1024 chunks)
    const int bidx = (t < 640) ? t : (t - 640);              // B chunk (640, dup 0..383)
    const int brow = bidx >> 2;
    const int bcol = ((bidx & 3) ^ ((brow >> 1) & 3)) * 8;
    const unsigned short* Abase = A + (size_t)bm * K;
    const unsigned short* Bbase = Bt + (size_t)bn * K;
    const int NP = K >> 5;

    int aoff[2], boff[5];
#pragma unroll
    for (int i = 0; i < 2; ++i) {
        int r = wm * 32 + i * 16 + l15;
        aoff[i] = r * 32 + ((lhi ^ ((r >> 1) & 3)) * 8);
    }
#pragma unroll
    for (int f = 0; f < 5; ++f) {
        int r = wn * 80 + f * 16 + l15;
        boff[f] = 8192 + r * 32 + ((lhi ^ ((r >> 1) & 3)) * 8);
    }

    f32x4 acc[2][5] = {};

#define STAGE_A(J) { const int j_ = (J);                                               \
    async_copy16(&S[j_ & 3][0] + t * 8,                                                \
                 Abase + (size_t)srow * K + j_ * 32 + scol); }
#define STAGE_B(J) { const int j_ = (J);                                               \
    async_copy16(&S[j_ & 3][8192] + bidx * 8,                                          \
                 Bbase + (size_t)brow * K + j_ * 32 + bcol); }

#define PERIOD(J, VM, DOSTAGE) {                                                       \
    const int jp_ = (J);                                                               \
    asm volatile("s_waitcnt vmcnt(" #VM ")" ::: "memory");                             \
    BAR();                                                                             \
    const unsigned short* sl = &S[jp_ & 3][0];                                         \
    if (DOSTAGE) STAGE_A(jp_ + 3);                                                     \
    bf16x8 bq[5], afr[2];                                                              \
    _Pragma("unroll")                                                                  \
    for (int f = 0; f < 5; ++f) bq[f] = *(const bf16x8*)(sl + boff[f]);                \
    afr[0] = *(const bf16x8*)(sl + aoff[0]);                                           \
    afr[1] = *(const bf16x8*)(sl + aoff[1]);                                           \
    if (DOSTAGE) STAGE_B(jp_ + 3);                                                     \
    __builtin_amdgcn_s_setprio(1);                                                     \
    _Pragma("unroll")                                                                  \
    for (int i = 0; i < 2; ++i)                                                        \
        _Pragma("unroll")                                                              \
        for (int f = 0; f < 5; ++f)                                                    \
            acc[i][f] = __builtin_amdgcn_mfma_f32_16x16x32_bf16(afr[i], bq[f],         \
                                                                acc[i][f], 0, 0, 0);   \
    __builtin_amdgcn_s_setprio(0); }

    STAGE_A(0); STAGE_B(0);
    STAGE_A(1); STAGE_B(1);
    STAGE_A(2); STAGE_B(2);

    for (int p = 0; p < NP - 3; ++p) {
        PERIOD(p, 4, 1);
    }
    PERIOD(NP - 3, 4, 0);
    PERIOD(NP - 2, 2, 0);
    PERIOD(NP - 1, 0, 0);

#undef PERIOD
#undef STAGE_A
#undef STAGE_B

#pragma unroll
    for (int f = 0; f < 5; ++f) {
        const int col = bn + wn * 80 + f * 16 + l15;
        const float bv = bias[col];
#pragma unroll
        for (int i = 0; i < 2; ++i) {
            const int row0 = bm + wm * 32 + i * 16 + lhi * 4;
#pragma unroll
            for (int r = 0; r < 4; ++r)
                C[(size_t)(row0 + r) * N + col] = acc[i][f][r] + bv;
        }
    }
}

// ---------------- pack qkv -> Q (rope+scale), K (rope), Vt; DPAD layout, pads unread ----------------
__global__ __launch_bounds__(256) void pack_rope_kernel(const unsigned short* __restrict__ qkv,
                                                        const int* __restrict__ pos_ids,
                                                        unsigned short* __restrict__ Qb,
                                                        unsigned short* __restrict__ Kb,
                                                        unsigned short* __restrict__ Vt) {
    int g = blockIdx.x * 256 + threadIdx.x;  // (b*32+h)*2048 + s
    int s = g & (SEQ - 1);
    int bh = g >> 11;
    int b = bh >> 5;
    int h = bh & 31;
    int m = b * SEQ + s;
    const unsigned short* base = qkv + (size_t)m * N_QKV + h * HDIM;
    unsigned short* Qrow = Qb + ((size_t)bh * SEQ + s) * DPAD;
    unsigned short* Krow = Kb + ((size_t)bh * SEQ + s) * DPAD;
    unsigned short* Vcol = Vt + (size_t)bh * HDIM * SEQ + s;

    float pos = (float)pos_ids[m];
    float qv[32], kv[32];
#pragma unroll
    for (int c = 0; c < 4; ++c) {
        ushort8 qc = *(const ushort8*)(base + c * 8);
        ushort8 kc = *(const ushort8*)(base + HIDDEN + c * 8);
#pragma unroll
        for (int j = 0; j < 8; ++j) {
            qv[c * 8 + j] = bf2f(qc[j]);
            kv[c * 8 + j] = bf2f(kc[j]);
        }
    }
#pragma unroll
    for (int d = 0; d < 16; ++d) {
        float inv = __expf(-(float)d * 0.5756462732485115f);  // ln(10000)/16
        float ang = pos * inv;
        float sn, cs;
        __sincosf(ang, &sn, &cs);
        float qcs = cs * ATT_SCALE, qsn = sn * ATT_SCALE;  // fold softmax scale into Q
        float x1 = qv[d], x2 = qv[d + 16];
        qv[d] = x1 * qcs - x2 * qsn;
        qv[d + 16] = x2 * qcs + x1 * qsn;
        x1 = kv[d]; x2 = kv[d + 16];
        kv[d] = x1 * cs - x2 * sn;
        kv[d + 16] = x2 * cs + x1 * sn;
    }
#pragma unroll
    for (int c = 0; c < 4; ++c) {
        ushort8 qo, ko;
#pragma unroll
        for (int j = 0; j < 8; ++j) {
            qo[j] = f2bf(qv[c * 8 + j]);
            ko[j] = f2bf(kv[c * 8 + j]);
        }
        *(ushort8*)(Qrow + c * 8) = qo;
        *(ushort8*)(Krow + c * 8) = ko;
    }
#pragma unroll
    for (int c = 4; c < 10; ++c) {
        ushort8 qc = *(const ushort8*)(base + c * 8);
        ushort8 qo;
#pragma unroll
        for (int j = 0; j < 8; ++j) qo[j] = f2bf(bf2f(qc[j]) * ATT_SCALE);
        *(ushort8*)(Qrow + c * 8) = qo;
        *(ushort8*)(Krow + c * 8) = *(const ushort8*)(base + HIDDEN + c * 8);
    }
    // pad columns 80..95 never read by flash -> no zero-fill
#pragma unroll
    for (int d = 0; d < HDIM; ++d) Vcol[(size_t)d * SEQ] = base[2 * HIDDEN + d];
}

// ---------------- causal flash attention v3.1: swapped QK^T, in-register softmax, D=80 exact ----------------
__global__ __launch_bounds__(512) void flash_kernel(const unsigned short* __restrict__ Qb,
                                                    const unsigned short* __restrict__ Kb,
                                                    const unsigned short* __restrict__ Vt,
                                                    unsigned short* __restrict__ attn) {
    __shared__ __align__(16) unsigned short Klds[64 * 128];
    __shared__ __align__(16) unsigned short Vlds[96 * 64];

    const int bh = blockIdx.x;
    const int qb = 7 - (int)blockIdx.y;  // heavy blocks dispatch first
    const int q0b = qb * 256;
    const int nkt = 4 * qb + 4;
    const int t = threadIdx.x;
    const int lane = t & 63, wid = t >> 6;
    const int l31 = lane & 31, h = lane >> 5, l7 = lane & 7;
    const int q0w = q0b + wid * 32;
    const int swz = l7 << 3;  // xor on shorts-offset (== (row&7)<<4 bytes)

    const unsigned short* Kbase = Kb + (size_t)bh * SEQ * DPAD;
    const unsigned short* Vbase = Vt + (size_t)bh * HDIM * SEQ;

    bf16x8 qf[5];
    {
        const unsigned short* Qrow = Qb + ((size_t)bh * SEQ + q0w + l31) * DPAD + h * 8;
#pragma unroll
        for (int dc = 0; dc < 5; ++dc) qf[dc] = *(const bf16x8*)(Qrow + dc * 16);
    }

    ((int*)Vlds)[2560 + t] = 0;  // zero V pad rows 80..95

    f32x16 acc0 = {}, acc1 = {}, acc2 = {};
    float mrow = -1e30f, lrow = 0.f;

    const int kidx1 = 512 + t;
    const int kr0 = t / 10, kc0 = t % 10;
    const int kr1 = kidx1 / 10, kc1 = kidx1 % 10;
    const int vr0 = t >> 3, vc0 = t & 7;
    const int vr1 = (512 + t) >> 3, vc1 = t & 7;
    const int kd0 = kr0 * 128 + ((kc0 * 8) ^ ((kr0 & 7) << 3));
    const int kd1 = kr1 * 128 + ((kc1 * 8) ^ ((kr1 & 7) << 3));
    const int vd0 = vr0 * 64 + ((vc0 * 8) ^ ((vr0 & 7) << 3));
    const int vd1 = vr1 * 64 + ((vc1 * 8) ^ ((vr1 & 7) << 3));

    ushort8 kreg0, kreg1, vreg0, vreg1;
    kreg0 = *(const ushort8*)(Kbase + (size_t)kr0 * DPAD + kc0 * 8);
    if (t < 128) kreg1 = *(const ushort8*)(Kbase + (size_t)kr1 * DPAD + kc1 * 8);
    vreg0 = *(const ushort8*)(Vbase + (size_t)vr0 * SEQ + vc0 * 8);
    if (t < 128) vreg1 = *(const ushort8*)(Vbase + (size_t)vr1 * SEQ + vc1 * 8);

    for (int kt = 0; kt < nkt; ++kt) {
        const int k0 = kt * 64;
        __syncthreads();
        *(ushort8*)(Klds + kd0) = kreg0;
        if (t < 128) *(ushort8*)(Klds + kd1) = kreg1;
        *(ushort8*)(Vlds + vd0) = vreg0;
        if (t < 128) *(ushort8*)(Vlds + vd1) = vreg1;
        __syncthreads();
        if (kt + 1 < nkt) {
            const int kn = k0 + 64;
            kreg0 = *(const ushort8*)(Kbase + (size_t)(kn + kr0) * DPAD + kc0 * 8);
            if (t < 128) kreg1 = *(const ushort8*)(Kbase + (size_t)(kn + kr1) * DPAD + kc1 * 8);
            vreg0 = *(const ushort8*)(Vbase + (size_t)vr0 * SEQ + kn + vc0 * 8);
            if (t < 128) vreg1 = *(const ushort8*)(Vbase + (size_t)vr1 * SEQ + kn + vc1 * 8);
        }
        if (k0 > q0w + 31) continue;

        f32x16 s0 = {}, s1 = {};
        __builtin_amdgcn_s_setprio(1);
#pragma unroll
        for (int dc = 0; dc < 5; ++dc) {
            const int co = (dc * 16 + h * 8) ^ swz;
            bf16x8 ka = *(const bf16x8*)(Klds + l31 * 128 + co);
            bf16x8 kb2 = *(const bf16x8*)(Klds + (32 + l31) * 128 + co);
            s0 = __builtin_amdgcn_mfma_f32_32x32x16_bf16(ka, qf[dc], s0, 0, 0, 0);
            s1 = __builtin_amdgcn_mfma_f32_32x32x16_bf16(kb2, qf[dc], s1, 0, 0, 0);
        }
        __builtin_amdgcn_s_setprio(0);

        const int qg = q0w + l31;
        if (k0 + 63 > q0w) {
#pragma unroll
            for (int r = 0; r < 16; ++r) {
                const int kg = k0 + (r & 3) + 8 * (r >> 2) + 4 * h;
                if (kg > qg) s0[r] = -2e30f;
                if (kg + 32 > qg) s1[r] = -2e30f;
            }
        }
        float pmax = s0[0];
#pragma unroll
        for (int r = 1; r < 16; ++r) pmax = fmaxf(pmax, s0[r]);
#pragma unroll
        for (int r = 0; r < 16; ++r) pmax = fmaxf(pmax, s1[r]);
        pmax = fmaxf(pmax, __shfl_xor(pmax, 32, 64));
        if (!__all(pmax <= mrow + 8.0f)) {
            float mnew = fmaxf(mrow, pmax);
            float scl = __expf(mrow - mnew);
            mrow = mnew;
            lrow *= scl;
#pragma unroll
            for (int r = 0; r < 16; ++r) {
                float sq = __shfl(scl, (r & 3) + 8 * (r >> 2) + 4 * h, 64);
                acc0[r] *= sq; acc1[r] *= sq; acc2[r] *= sq;
            }
        }
        float ps = 0.f;
#pragma unroll
        for (int r = 0; r < 16; ++r) { s0[r] = __expf(s0[r] - mrow); ps += s0[r]; }
#pragma unroll
        for (int r = 0; r < 16; ++r) { s1[r] = __expf(s1[r] - mrow); ps += s1[r]; }
        lrow += ps + __shfl_xor(ps, 32, 64);
        i32x4 af[2][2];
#pragma unroll
        for (int ks = 0; ks < 2; ++ks) {
            const f32x16& sv = ks ? s1 : s0;
            int pk0[2], pk1[2], pk2[2], pk3[2];
#pragma unroll
            for (int i = 0; i < 2; ++i) {
                pk0[i] = cvt_pk_bf16(sv[2 * i], sv[2 * i + 1]);
                pk1[i] = cvt_pk_bf16(sv[4 + 2 * i], sv[5 + 2 * i]);
                pk2[i] = cvt_pk_bf16(sv[8 + 2 * i], sv[9 + 2 * i]);
                pk3[i] = cvt_pk_bf16(sv[12 + 2 * i], sv[13 + 2 * i]);
            }
#pragma unroll
            for (int i = 0; i < 2; ++i) {
                const int o0 = __shfl_xor(pk0[i], 32, 64);
                const int o1 = __shfl_xor(pk1[i], 32, 64);
                af[ks][0][i]     = h ? o1     : pk0[i];
                af[ks][0][2 + i] = h ? pk1[i] : o0;
                const int o2 = __shfl_xor(pk2[i], 32, 64);
                const int o3 = __shfl_xor(pk3[i], 32, 64);
                af[ks][1][i]     = h ? o3     : pk2[i];
                af[ks][1][2 + i] = h ? pk3[i] : o2;
            }
        }
        __builtin_amdgcn_s_setprio(1);
#pragma unroll
        for (int ds = 0; ds < 3; ++ds) {
            f32x16& ac = ds == 0 ? acc0 : (ds == 1 ? acc1 : acc2);
            const int vrow = (ds * 32 + l31) * 64;
#pragma unroll
            for (int ks = 0; ks < 2; ++ks)
#pragma unroll
                for (int kh = 0; kh < 2; ++kh) {
                    bf16x8 vb = *(const bf16x8*)(Vlds + vrow + ((ks * 32 + kh * 16 + h * 8) ^ swz));
                    bf16x8 pa = __builtin_bit_cast(bf16x8, af[ks][kh]);
                    ac = __builtin_amdgcn_mfma_f32_32x32x16_bf16(pa, vb, ac, 0, 0, 0);
                }
        }
        __builtin_amdgcn_s_setprio(0);
    }

    const int hh = bh & 31, b = bh >> 5;
    const float linv = 1.0f / lrow;
#pragma unroll
    for (int r = 0; r < 16; ++r) {
        const int ql = (r & 3) + 8 * (r >> 2) + 4 * h;
        const float lv = __shfl(linv, ql, 64);
        const int row = b * SEQ + q0b + wid * 32 + ql;
        unsigned short* orow = attn + (size_t)row * HIDDEN + hh * HDIM;
        orow[l31] = f2bf(acc0[r] * lv);
        orow[32 + l31] = f2bf(acc1[r] * lv);
        if (l31 < 16) orow[64 + l31] = f2bf(acc2[r] * lv);
    }
}

extern "C" void kernel_launch(void* const* d_in, const int* in_sizes, int n_in,
                              void* d_out, int out_size, void* d_ws, size_t ws_size,
                              hipStream_t stream) {
    const int* pos = (const int*)d_in[0];
    const float* hid = (const float*)d_in[1];
    const float* Wqkv = (const float*)d_in[2];
    const float* bqkv = (const float*)d_in[3];
    const float* Wd = (const float*)d_in[4];
    const float* bd = (const float*)d_in[5];
    float* out = (float*)d_out;
    char* ws = (char*)d_ws;

    unsigned short* WqkvT = (unsigned short*)(ws);                // 39,321,600 B
    unsigned short* WdT   = (unsigned short*)(ws + 39321600);     // 13,107,200 B
    unsigned short* Xbf   = (unsigned short*)(ws + 52428800);     // 20,971,520 B
    unsigned short* qkv   = (unsigned short*)(ws + 73400320);     // 62,914,560 B
    unsigned short* Qbuf  = (unsigned short*)(ws + 136314880);    // 25,165,824 B
    unsigned short* Kbuf  = (unsigned short*)(ws + 161480704);    // 25,165,824 B
    unsigned short* Vt    = (unsigned short*)(ws + 186646528);    // 20,971,520 B
    unsigned short* attnb = Xbf;  // Xbf dead after gemm1; reuse for attention output

    cvt_kernel<<<(M_TOK * HIDDEN / 8 + 255) / 256, 256, 0, stream>>>(hid, Xbf, M_TOK * HIDDEN / 8);
    transpose_kernel<<<dim3(N_QKV / 64, HIDDEN / 64), 256, 0, stream>>>(Wqkv, WqkvT, HIDDEN, N_QKV);
    transpose_kernel<<<dim3(HIDDEN / 64, HIDDEN / 64), 256, 0, stream>>>(Wd, WdT, HIDDEN, HIDDEN);
    gemm256<1><<<(M_TOK / 256) * (N_QKV / 256), 1024, 0, stream>>>(Xbf, WqkvT, bqkv, qkv,
                                                                   M_TOK, N_QKV, HIDDEN);
    pack_rope_kernel<<<(64 * SEQ) / 256, 256, 0, stream>>>(qkv, pos, Qbuf, Kbuf, Vt);
    flash_kernel<<<dim3(64, 8), 512, 0, stream>>>(Qbuf, Kbuf, Vt, attnb);
    gemm160<<<(M_TOK / 256) * (HIDDEN / 160), 1024, 0, stream>>>(attnb, WdT, bd, out,
                                                                 M_TOK, HIDDEN, HIDDEN);
}